// Round 1
// baseline (676.240 us; speedup 1.0000x reference)
//
#include <hip/hip_runtime.h>

#define T_STEPS 4096
#define BATCH   2048
#define HID     10
#define UNROLL  16

// tanh(a) = 1 - 2/(exp(2a)+1); v_exp + v_rcp, saturates correctly:
// a -> +inf: exp=inf, rcp=0, h=1.  a -> -inf: exp=0, rcp=1, h=-1.
__device__ __forceinline__ float tanh_fast(float a) {
    float e = __expf(a + a);
    float r = __builtin_amdgcn_rcpf(e + 1.0f);
    return fmaf(-2.0f, r, 1.0f);
}

__global__ __launch_bounds__(64) void rnn_kernel(
    const float* __restrict__ x,
    const float* __restrict__ h0,
    const float* __restrict__ W_ih,
    const float* __restrict__ b_ih,
    const float* __restrict__ W_hh,
    const float* __restrict__ b_hh,
    const float* __restrict__ W_out,
    const float* __restrict__ b_out,
    float* __restrict__ out)
{
    // 4 batch groups of 16 lanes per 64-thread block (one wave).
    __shared__ __align__(16) float hbuf[64];

    const int tid = threadIdx.x;          // 0..63
    const int g   = tid >> 4;             // group 0..3
    const int j   = tid & 15;             // lane-in-group; j<10 owns h_j
    const int b   = (blockIdx.x << 2) + g; // batch element
    const bool jv = (j < HID);
    const int jc  = jv ? j : 0;           // clamped index (avoid OOB loads)

    // Per-lane weights: row j of W_hh, W_ih[j], fused bias. Idle lanes get 0
    // so their h stays exactly 0 (tanh_fast(0)==0).
    const float wih = jv ? W_ih[jc] : 0.0f;
    const float bj  = jv ? (b_ih[jc] + b_hh[jc]) : 0.0f;
    float w[HID];
#pragma unroll
    for (int k = 0; k < HID; ++k) w[k] = jv ? W_hh[jc * HID + k] : 0.0f;
    float wo[HID];
#pragma unroll
    for (int k = 0; k < HID; ++k) wo[k] = W_out[k];
    const float bo = b_out[0];

    float* slot = &hbuf[g * 16];

    // h_0 into LDS (input h is zeros, but read it for robustness).
    float hval = jv ? h0[b * HID + jc] : 0.0f;
    slot[j] = hval;
    __asm__ __volatile__("" ::: "memory");   // write visible before first gather

    // x prefetch pipeline: UNROLL steps (~16*110 cyc) covers HBM latency.
    float xbuf[UNROLL];
#pragma unroll
    for (int u = 0; u < UNROLL; ++u) xbuf[u] = x[(size_t)u * BATCH + b];

    for (int t0 = 0; t0 < T_STEPS; t0 += UNROLL) {
#pragma unroll
        for (int u = 0; u < UNROLL; ++u) {
            const int t = t0 + u;

            // issue next x load early (off critical path; clamp to avoid OOB)
            const int tp = (t + UNROLL < T_STEPS) ? (t + UNROLL) : 0;
            const float xnext = x[(size_t)tp * BATCH + b];

            // gather h_t from LDS (written end of previous step; same-wave DS
            // ops are in-order in HW, clobbers pin compiler ordering)
            const float4 p0 = *reinterpret_cast<const float4*>(slot);
            const float4 p1 = *reinterpret_cast<const float4*>(slot + 4);
            const float2 p2 = *reinterpret_cast<const float2*>(slot + 8);

            // out[t-1] = W_out . h_t + b_out  (off critical path; t==0 writes
            // a dummy to row 0, overwritten at t==1 — same lane, same addr,
            // per-location coherence guarantees program order)
            float ov = bo;
            ov = fmaf(wo[0], p0.x, ov); ov = fmaf(wo[1], p0.y, ov);
            ov = fmaf(wo[2], p0.z, ov); ov = fmaf(wo[3], p0.w, ov);
            ov = fmaf(wo[4], p1.x, ov); ov = fmaf(wo[5], p1.y, ov);
            ov = fmaf(wo[6], p1.z, ov); ov = fmaf(wo[7], p1.w, ov);
            ov = fmaf(wo[8], p2.x, ov); ov = fmaf(wo[9], p2.y, ov);
            if (j == 0) {
                const int row = (t > 0) ? (t - 1) : 0;
                out[(size_t)row * BATCH + b] = ov;
            }

            // h_{t+1} = tanh(W_ih*x_t + b + W_hh . h_t): two 5-FMA chains
            const float xc = xbuf[u];
            float s0 = fmaf(wih, xc, bj);
            s0 = fmaf(w[0], p0.x, s0);
            s0 = fmaf(w[1], p0.y, s0);
            s0 = fmaf(w[2], p0.z, s0);
            s0 = fmaf(w[3], p0.w, s0);
            s0 = fmaf(w[4], p1.x, s0);
            float s1 =      w[5] * p1.y;
            s1 = fmaf(w[6], p1.z, s1);
            s1 = fmaf(w[7], p1.w, s1);
            s1 = fmaf(w[8], p2.x, s1);
            s1 = fmaf(w[9], p2.y, s1);
            hval = tanh_fast(s0 + s1);

            slot[j] = hval;
            __asm__ __volatile__("" ::: "memory");  // write before next gather

            xbuf[u] = xnext;
        }
    }

    // Epilogue: out[T-1] from h_T, and h_last.
    {
        const float4 p0 = *reinterpret_cast<const float4*>(slot);
        const float4 p1 = *reinterpret_cast<const float4*>(slot + 4);
        const float2 p2 = *reinterpret_cast<const float2*>(slot + 8);
        float ov = bo;
        ov = fmaf(wo[0], p0.x, ov); ov = fmaf(wo[1], p0.y, ov);
        ov = fmaf(wo[2], p0.z, ov); ov = fmaf(wo[3], p0.w, ov);
        ov = fmaf(wo[4], p1.x, ov); ov = fmaf(wo[5], p1.y, ov);
        ov = fmaf(wo[6], p1.z, ov); ov = fmaf(wo[7], p1.w, ov);
        ov = fmaf(wo[8], p2.x, ov); ov = fmaf(wo[9], p2.y, ov);
        if (j == 0) out[(size_t)(T_STEPS - 1) * BATCH + b] = ov;
        // h_last: lane j already holds h_T[j]
        if (jv) out[(size_t)T_STEPS * BATCH + (size_t)b * HID + j] = hval;
    }
}

extern "C" void kernel_launch(void* const* d_in, const int* in_sizes, int n_in,
                              void* d_out, int out_size, void* d_ws, size_t ws_size,
                              hipStream_t stream) {
    const float* x     = (const float*)d_in[0];
    const float* h0    = (const float*)d_in[1];
    const float* W_ih  = (const float*)d_in[2];
    const float* b_ih  = (const float*)d_in[3];
    const float* W_hh  = (const float*)d_in[4];
    const float* b_hh  = (const float*)d_in[5];
    const float* W_out = (const float*)d_in[6];
    const float* b_out = (const float*)d_in[7];

    rnn_kernel<<<BATCH / 4, 64, 0, stream>>>(
        x, h0, W_ih, b_ih, W_hh, b_hh, W_out, b_out, (float*)d_out);
}

// Round 2
// 629.143 us; speedup vs baseline: 1.0749x; 1.0749x over previous
//
#include <hip/hip_runtime.h>

#define T_STEPS 4096
#define BATCH   2048
#define HID     10
#define UNROLL  16

// DPP row rotate-right by N within each 16-lane row: lane n receives the
// value from lane (n-N)&15 (same direction family as row_shr, per the GCN
// inclusive-scan idiom). Our 16-lane batch groups align exactly with DPP rows.
template<int N>
__device__ __forceinline__ float ror16(float v) {
    int r = __builtin_amdgcn_update_dpp(
        0, __builtin_bit_cast(int, v), 0x120 | N, 0xF, 0xF, false);
    return __builtin_bit_cast(float, r);
}

// tanh(a) = 1 - 2/(exp(2a)+1); v_exp + v_rcp, saturates correctly:
// a -> +inf: exp=inf, rcp=0, h=1.  a -> -inf: exp=0, rcp=1, h=-1.
// tanh_fast(0) == 0 exactly (idle lanes stay 0).
__device__ __forceinline__ float tanh_fast(float a) {
    float e = __expf(a + a);
    float r = __builtin_amdgcn_rcpf(e + 1.0f);
    return fmaf(-2.0f, r, 1.0f);
}

__global__ __launch_bounds__(64) void rnn_kernel(
    const float* __restrict__ x,
    const float* __restrict__ h0,
    const float* __restrict__ W_ih,
    const float* __restrict__ b_ih,
    const float* __restrict__ W_hh,
    const float* __restrict__ b_hh,
    const float* __restrict__ W_out,
    const float* __restrict__ b_out,
    float* __restrict__ out)
{
    const int tid = threadIdx.x;            // 0..63
    const int j   = tid & 15;               // lane-in-group; j<10 owns h_j
    const int b   = (blockIdx.x << 2) + (tid >> 4);
    const bool jv = (j < HID);
    const int jc  = jv ? j : 0;

    // Per-lane constants. Idle lanes (j>=10) get all-zero weights so their
    // h stays exactly 0 and contributes nothing.
    const float wih  = jv ? W_ih[jc] : 0.0f;
    const float bj   = jv ? (b_ih[jc] + b_hh[jc]) : 0.0f;
    const float wo_j = jv ? W_out[jc] : 0.0f;
    const float bo   = b_out[0];

    // Pre-permuted W_hh row: wsh[N] pairs with ror16<N>(h), which delivers
    // h[(j-N)&15] to lane j.
    float wsh[16];
#pragma unroll
    for (int N = 0; N < 16; ++N) {
        const int k = (j - N) & 15;
        wsh[N] = (jv && k < HID) ? W_hh[jc * HID + k] : 0.0f;
    }

    float hval = jv ? h0[b * HID + jc] : 0.0f;

    // x prefetch pipeline: UNROLL steps ahead covers HBM latency.
    float xbuf[UNROLL];
#pragma unroll
    for (int u = 0; u < UNROLL; ++u) xbuf[u] = x[(size_t)u * BATCH + b];

    for (int t0 = 0; t0 < T_STEPS; t0 += UNROLL) {
#pragma unroll
        for (int u = 0; u < UNROLL; ++u) {
            const int t = t0 + u;
            const int tp = (t + UNROLL < T_STEPS) ? (t + UNROLL) : 0;
            const float xnext = x[(size_t)tp * BATCH + b];

            // Cross-lane gather of h via independent DPP rotations (VALU pipe,
            // no LDS, no waitcnt).
            const float hr1  = ror16<1>(hval);
            const float hr2  = ror16<2>(hval);
            const float hr3  = ror16<3>(hval);
            const float hr4  = ror16<4>(hval);
            const float hr5  = ror16<5>(hval);
            const float hr6  = ror16<6>(hval);
            const float hr7  = ror16<7>(hval);
            const float hr8  = ror16<8>(hval);
            const float hr9  = ror16<9>(hval);
            const float hr10 = ror16<10>(hval);
            const float hr11 = ror16<11>(hval);
            const float hr12 = ror16<12>(hval);
            const float hr13 = ror16<13>(hval);
            const float hr14 = ror16<14>(hval);
            const float hr15 = ror16<15>(hval);

            // h_{t+1} = tanh(wih*x_t + b + W_hh . h_t): 4 parallel 4-FMA chains
            float a0 = fmaf(wih, xbuf[u], bj);      // ready early (x in reg)
            a0 = fmaf(wsh[0], hval, a0);
            a0 = fmaf(wsh[1], hr1,  a0);
            a0 = fmaf(wsh[2], hr2,  a0);
            a0 = fmaf(wsh[3], hr3,  a0);
            float a1 =      wsh[4] * hr4;
            a1 = fmaf(wsh[5], hr5,  a1);
            a1 = fmaf(wsh[6], hr6,  a1);
            a1 = fmaf(wsh[7], hr7,  a1);
            float a2 =      wsh[8] * hr8;
            a2 = fmaf(wsh[9],  hr9,  a2);
            a2 = fmaf(wsh[10], hr10, a2);
            a2 = fmaf(wsh[11], hr11, a2);
            float a3 =      wsh[12] * hr12;
            a3 = fmaf(wsh[13], hr13, a3);
            a3 = fmaf(wsh[14], hr14, a3);
            a3 = fmaf(wsh[15], hr15, a3);
            hval = tanh_fast((a0 + a1) + (a2 + a3));

            // out[t] = W_out . h_{t+1} + b_out via rotation all-reduce
            // (ror:8 is an exact xor-8 butterfly; 4,2,1 finish by progressive
            // periodicity — every lane ends with the full group sum).
            // Off the recurrence critical path.
            float p = wo_j * hval;
            p += ror16<8>(p);
            p += ror16<4>(p);
            p += ror16<2>(p);
            p += ror16<1>(p);
            out[(size_t)t * BATCH + b] = p + bo;  // all 16 lanes, same addr

            xbuf[u] = xnext;
        }
    }

    // h_last: lane j holds h_T[j]
    if (jv) out[(size_t)T_STEPS * BATCH + (size_t)b * HID + j] = hval;
}

extern "C" void kernel_launch(void* const* d_in, const int* in_sizes, int n_in,
                              void* d_out, int out_size, void* d_ws, size_t ws_size,
                              hipStream_t stream) {
    const float* x     = (const float*)d_in[0];
    const float* h0    = (const float*)d_in[1];
    const float* W_ih  = (const float*)d_in[2];
    const float* b_ih  = (const float*)d_in[3];
    const float* W_hh  = (const float*)d_in[4];
    const float* b_hh  = (const float*)d_in[5];
    const float* W_out = (const float*)d_in[6];
    const float* b_out = (const float*)d_in[7];

    rnn_kernel<<<BATCH / 4, 64, 0, stream>>>(
        x, h0, W_ih, b_ih, W_hh, b_hh, W_out, b_out, (float*)d_out);
}

// Round 3
// 540.932 us; speedup vs baseline: 1.2501x; 1.1631x over previous
//
#include <hip/hip_runtime.h>

#define T_STEPS 4096
#define BATCH   2048
#define HID     10
#define UB      16   // steps per block: load/store batching granularity

// DPP row rotate-right by N within each 16-lane row: lane n receives the
// value from lane (n-N)&15. Encoding 0x120|N = row_ror:N (HW-verified in R2).
template<int N>
__device__ __forceinline__ float ror16(float v) {
    int r = __builtin_amdgcn_update_dpp(
        0, __builtin_bit_cast(int, v), 0x120 | N, 0xF, 0xF, false);
    return __builtin_bit_cast(float, r);
}

// tanh(a) = 1 - 2/(exp(2a)+1); v_exp + v_rcp, saturates correctly at +/-inf.
// tanh_fast(0) == 0 exactly (idle lanes stay 0).
__device__ __forceinline__ float tanh_fast(float a) {
    float e = __expf(a + a);
    float r = __builtin_amdgcn_rcpf(e + 1.0f);
    return fmaf(-2.0f, r, 1.0f);
}

__global__ __launch_bounds__(64) void rnn_kernel(
    const float* __restrict__ x,
    const float* __restrict__ h0,
    const float* __restrict__ W_ih,
    const float* __restrict__ b_ih,
    const float* __restrict__ W_hh,
    const float* __restrict__ b_hh,
    const float* __restrict__ W_out,
    const float* __restrict__ b_out,
    float* __restrict__ out)
{
    const int tid = threadIdx.x;            // 0..63
    const int j   = tid & 15;               // lane-in-group; j<10 owns h_j
    const int b   = (blockIdx.x << 2) + (tid >> 4);
    const bool jv = (j < HID);
    const int jc  = jv ? j : 0;

    // Per-lane constants; idle lanes (j>=10) get zero weights so h stays 0.
    const float wih  = jv ? W_ih[jc] : 0.0f;
    const float bj   = jv ? (b_ih[jc] + b_hh[jc]) : 0.0f;
    const float wo_j = jv ? W_out[jc] : 0.0f;
    const float bo   = b_out[0];

    // Pre-permuted W_hh row: wsh[N] pairs with ror16<N>(h) = h[(j-N)&15].
    float wsh[16];
#pragma unroll
    for (int N = 0; N < 16; ++N) {
        const int k = (j - N) & 15;
        wsh[N] = (jv && k < HID) ? W_hh[jc * HID + k] : 0.0f;
    }

    float hval = jv ? h0[b * HID + jc] : 0.0f;

    // Block-0 x values (each group's 16 lanes redundantly load same addr).
    const float* xb = x + b;
    float xcur[UB];
#pragma unroll
    for (int u = 0; u < UB; ++u) xcur[u] = xb[(size_t)u * BATCH];

    for (int t0 = 0; t0 < T_STEPS; t0 += UB) {
        // Prefetch next block's x (16 loads back-to-back; one vmcnt region
        // per 16 steps). Last block harmlessly reloads block 0.
        const float* xsrc = (t0 + UB < T_STEPS)
                          ? (xb + (size_t)(t0 + UB) * BATCH) : xb;
        float xnxt[UB];
#pragma unroll
        for (int u = 0; u < UB; ++u) xnxt[u] = xsrc[(size_t)u * BATCH];

        float pkeep = 0.0f;
#pragma unroll
        for (int u = 0; u < UB; ++u) {
            // Cross-lane gather of h via independent DPP rotations (VALU only).
            const float hr1  = ror16<1>(hval);
            const float hr2  = ror16<2>(hval);
            const float hr3  = ror16<3>(hval);
            const float hr4  = ror16<4>(hval);
            const float hr5  = ror16<5>(hval);
            const float hr6  = ror16<6>(hval);
            const float hr7  = ror16<7>(hval);
            const float hr8  = ror16<8>(hval);
            const float hr9  = ror16<9>(hval);
            const float hr10 = ror16<10>(hval);
            const float hr11 = ror16<11>(hval);
            const float hr12 = ror16<12>(hval);
            const float hr13 = ror16<13>(hval);
            const float hr14 = ror16<14>(hval);
            const float hr15 = ror16<15>(hval);

            // h_{t+1} = tanh(wih*x_t + b + W_hh . h_t): 4 parallel FMA chains.
            float a0 = fmaf(wih, xcur[u], bj);
            a0 = fmaf(wsh[0], hval, a0);
            a0 = fmaf(wsh[1], hr1,  a0);
            a0 = fmaf(wsh[2], hr2,  a0);
            a0 = fmaf(wsh[3], hr3,  a0);
            float a1 =      wsh[4] * hr4;
            a1 = fmaf(wsh[5], hr5,  a1);
            a1 = fmaf(wsh[6], hr6,  a1);
            a1 = fmaf(wsh[7], hr7,  a1);
            float a2 =      wsh[8] * hr8;
            a2 = fmaf(wsh[9],  hr9,  a2);
            a2 = fmaf(wsh[10], hr10, a2);
            a2 = fmaf(wsh[11], hr11, a2);
            float a3 =      wsh[12] * hr12;
            a3 = fmaf(wsh[13], hr13, a3);
            a3 = fmaf(wsh[14], hr14, a3);
            a3 = fmaf(wsh[15], hr15, a3);
            hval = tanh_fast((a0 + a1) + (a2 + a3));

            // out reduce: rotation all-reduce; every lane gets the group sum.
            float p = wo_j * hval;
            p += ror16<8>(p);
            p += ror16<4>(p);
            p += ror16<2>(p);
            p += ror16<1>(p);
            if (j == u) pkeep = p;   // lane-cycled keep (1 cndmask)
        }

        // One store per 16 steps: lane j writes out(t0+j, b). 64 distinct
        // addresses across the wave, single global_store_dword.
        out[(size_t)(t0 + j) * BATCH + b] = pkeep + bo;

#pragma unroll
        for (int u = 0; u < UB; ++u) xcur[u] = xnxt[u];
    }

    // h_last: lane j holds h_T[j]
    if (jv) out[(size_t)T_STEPS * BATCH + (size_t)b * HID + j] = hval;
}

extern "C" void kernel_launch(void* const* d_in, const int* in_sizes, int n_in,
                              void* d_out, int out_size, void* d_ws, size_t ws_size,
                              hipStream_t stream) {
    const float* x     = (const float*)d_in[0];
    const float* h0    = (const float*)d_in[1];
    const float* W_ih  = (const float*)d_in[2];
    const float* b_ih  = (const float*)d_in[3];
    const float* W_hh  = (const float*)d_in[4];
    const float* b_hh  = (const float*)d_in[5];
    const float* W_out = (const float*)d_in[6];
    const float* b_out = (const float*)d_in[7];

    rnn_kernel<<<BATCH / 4, 64, 0, stream>>>(
        x, h0, W_ih, b_ih, W_hh, b_hh, W_out, b_out, (float*)d_out);
}

// Round 5
// 533.677 us; speedup vs baseline: 1.2671x; 1.0136x over previous
//
#include <hip/hip_runtime.h>

#define T_STEPS 4096
#define BATCH   2048
#define HID     10
#define UB      16   // steps per block: load/store batching granularity

// DPP row rotate-right by N within each 16-lane row: lane n receives the
// value from lane (n-N)&15. Encoding 0x120|N = row_ror:N (HW-verified R2/R3).
template<int N>
__device__ __forceinline__ float ror16(float v) {
    int r = __builtin_amdgcn_update_dpp(
        0, __builtin_bit_cast(int, v), 0x120 | N, 0xF, 0xF, false);
    return __builtin_bit_cast(float, r);
}

// tanh(a) = 1 - 2/(exp2(C*a)+1), C = 2*log2(e). v_mul + v_exp + v_add +
// v_rcp + v_fma. Saturates correctly at +/-inf; tanh_fast(0)==0 exactly.
__device__ __forceinline__ float tanh_fast(float a) {
    float e = __builtin_amdgcn_exp2f(a * 2.88539008177792681472f);
    float r = __builtin_amdgcn_rcpf(e + 1.0f);
    return fmaf(-2.0f, r, 1.0f);
}

// (64,1): 1 wave min per EU -> full 512-VGPR budget. Occupancy is irrelevant
// (512 waves on 1024 SIMDs); what matters is keeping the x double-buffer and
// all weights resident so the steady-state step is pure VALU. R3's default
// budget (VGPR=48) forced per-step reloads of x — the ~165 cyc/step stall.
__global__ __launch_bounds__(64, 1) void rnn_kernel(
    const float* __restrict__ x,
    const float* __restrict__ h0,
    const float* __restrict__ W_ih,
    const float* __restrict__ b_ih,
    const float* __restrict__ W_hh,
    const float* __restrict__ b_hh,
    const float* __restrict__ W_out,
    const float* __restrict__ b_out,
    float* __restrict__ out)
{
    const int tid = threadIdx.x;            // 0..63
    const int j   = tid & 15;               // lane-in-group; j<10 owns h_j
    const int b   = (blockIdx.x << 2) + (tid >> 4);
    const bool jv = (j < HID);
    const int jc  = jv ? j : 0;

    // Per-lane constants; idle lanes (j>=10) get zero weights so h stays 0.
    const float wih  = jv ? W_ih[jc] : 0.0f;
    const float bj   = jv ? (b_ih[jc] + b_hh[jc]) : 0.0f;
    const float wo_j = jv ? W_out[jc] : 0.0f;
    const float bo   = b_out[0];

    // Pre-permuted W_hh row: wsh[N] pairs with ror16<N>(h) = h[(j-N)&15].
    float wsh[16];
#pragma unroll
    for (int N = 0; N < 16; ++N) {
        const int k = (j - N) & 15;
        wsh[N] = (jv && k < HID) ? W_hh[jc * HID + k] : 0.0f;
    }

    float hval = jv ? h0[b * HID + jc] : 0.0f;

    // Block-0 x values (group's 16 lanes redundantly load the same addr).
    const float* xb = x + b;
    float xcur[UB];
#pragma unroll
    for (int u = 0; u < UB; ++u) xcur[u] = xb[(size_t)u * BATCH];

    for (int t0 = 0; t0 < T_STEPS; t0 += UB) {
        // Prefetch next block's x: 16 loads back-to-back, consumed ~1800 cyc
        // later — one vmcnt region per 16 steps. Last block reloads block 0
        // (harmless).
        const float* xsrc = (t0 + UB < T_STEPS)
                          ? (xb + (size_t)(t0 + UB) * BATCH) : xb;
        float xnxt[UB];
#pragma unroll
        for (int u = 0; u < UB; ++u) xnxt[u] = xsrc[(size_t)u * BATCH];

        float pkeep = 0.0f;
#pragma unroll
        for (int u = 0; u < UB; ++u) {
            // Cross-lane gather of h via independent DPP rotations (VALU only).
            const float hr1  = ror16<1>(hval);
            const float hr2  = ror16<2>(hval);
            const float hr3  = ror16<3>(hval);
            const float hr4  = ror16<4>(hval);
            const float hr5  = ror16<5>(hval);
            const float hr6  = ror16<6>(hval);
            const float hr7  = ror16<7>(hval);
            const float hr8  = ror16<8>(hval);
            const float hr9  = ror16<9>(hval);
            const float hr10 = ror16<10>(hval);
            const float hr11 = ror16<11>(hval);
            const float hr12 = ror16<12>(hval);
            const float hr13 = ror16<13>(hval);
            const float hr14 = ror16<14>(hval);
            const float hr15 = ror16<15>(hval);

            // h_{t+1} = tanh(wih*x_t + b + W_hh . h_t): two 8-FMA chains.
            float a0 = fmaf(wih, xcur[u], bj);
            a0 = fmaf(wsh[0], hval, a0);
            a0 = fmaf(wsh[1], hr1,  a0);
            a0 = fmaf(wsh[2], hr2,  a0);
            a0 = fmaf(wsh[3], hr3,  a0);
            a0 = fmaf(wsh[4], hr4,  a0);
            a0 = fmaf(wsh[5], hr5,  a0);
            a0 = fmaf(wsh[6], hr6,  a0);
            a0 = fmaf(wsh[7], hr7,  a0);
            float a1 =      wsh[8] * hr8;
            a1 = fmaf(wsh[9],  hr9,  a1);
            a1 = fmaf(wsh[10], hr10, a1);
            a1 = fmaf(wsh[11], hr11, a1);
            a1 = fmaf(wsh[12], hr12, a1);
            a1 = fmaf(wsh[13], hr13, a1);
            a1 = fmaf(wsh[14], hr14, a1);
            a1 = fmaf(wsh[15], hr15, a1);
            hval = tanh_fast(a0 + a1);

            // out reduce: rotation all-reduce; every lane gets the group sum.
            float p = wo_j * hval;
            p += ror16<8>(p);
            p += ror16<4>(p);
            p += ror16<2>(p);
            p += ror16<1>(p);
            if (j == u) pkeep = p;   // lane-cycled keep
        }

        // One store per 16 steps: lane j writes out(t0+j, b).
        out[(size_t)(t0 + j) * BATCH + b] = pkeep + bo;

#pragma unroll
        for (int u = 0; u < UB; ++u) xcur[u] = xnxt[u];
    }

    // h_last: lane j holds h_T[j]
    if (jv) out[(size_t)T_STEPS * BATCH + (size_t)b * HID + j] = hval;
}

extern "C" void kernel_launch(void* const* d_in, const int* in_sizes, int n_in,
                              void* d_out, int out_size, void* d_ws, size_t ws_size,
                              hipStream_t stream) {
    const float* x     = (const float*)d_in[0];
    const float* h0    = (const float*)d_in[1];
    const float* W_ih  = (const float*)d_in[2];
    const float* b_ih  = (const float*)d_in[3];
    const float* W_hh  = (const float*)d_in[4];
    const float* b_hh  = (const float*)d_in[5];
    const float* W_out = (const float*)d_in[6];
    const float* b_out = (const float*)d_in[7];

    rnn_kernel<<<BATCH / 4, 64, 0, stream>>>(
        x, h0, W_ih, b_ih, W_hh, b_hh, W_out, b_out, (float*)d_out);
}